// Round 1
// baseline (1691.122 us; speedup 1.0000x reference)
//
#include <hip/hip_runtime.h>
#include <math.h>

// DP-means on MI355X. State machine across 50 graph-captured iterations,
// frozen via device-side `done` flag (matches reference tree_map freeze).
// mu lives directly in d_out (64x1024 fp32). Two X passes per live iteration.

#define NPTS   65536
#define DDIM   1024
#define KMAX   64
#define LAMBDA_F 1000.0f
#define INF_F  1e30f

struct Scal {
  int K, it, done, create, Kc, Knew, farcnt, _pad;
  double prev_obj, s_all, s_far, sx2far;
};

// ---------------- init kernels ----------------

__global__ void kZpre(Scal* sc, double* musum) {
  int tid = threadIdx.x;
  #pragma unroll
  for (int r = 0; r < 4; ++r) musum[(r << 8) + tid] = 0.0;
  if (tid == 0) {
    sc->K = 1; sc->it = 0; sc->done = 0; sc->create = 0; sc->Kc = 0; sc->Knew = 1;
    sc->farcnt = 0; sc->prev_obj = 0.0; sc->s_all = 0.0; sc->s_far = 0.0; sc->sx2far = 0.0;
  }
}

// x2[p] = sum_d x[p][d]^2  (one wave per point, shuffle tree)
__global__ __launch_bounds__(256) void kZ1(const float* __restrict__ X, float* __restrict__ x2) {
  const int tid = threadIdx.x, lane = tid & 63, wv = tid >> 6;
  const int p = (blockIdx.x << 2) + wv;
  const float* row = X + ((size_t)p << 10);
  float s = 0.f;
  #pragma unroll
  for (int c = 0; c < 4; ++c) {
    float4 v = *(const float4*)&row[(c << 8) + (lane << 2)];
    s += v.x * v.x + v.y * v.y + v.z * v.z + v.w * v.w;
  }
  #pragma unroll
  for (int m = 1; m < 64; m <<= 1) s += __shfl_xor(s, m);
  if (lane == 0) x2[p] = s;
}

// column partial sums for mu0 (mean of X), fp64 atomics into musum
__global__ __launch_bounds__(256) void kZ2(const float* __restrict__ X, double* __restrict__ musum) {
  const int tid = threadIdx.x;
  const int dcb = blockIdx.x & 3, nb = blockIdx.x >> 2;
  const int d = (dcb << 8) + tid;
  const float* xp = X + ((size_t)nb << 20) + d;
  float s = 0.f;
  for (int p = 0; p < 1024; ++p) s += xp[(size_t)p << 10];
  unsafeAtomicAdd(&musum[d], (double)s);
}

// finalize init: mu[0]=mean, mu[k>0]=0, m2
__global__ __launch_bounds__(256) void kZ3(const double* __restrict__ musum,
                                           float* __restrict__ mu, float* __restrict__ m2) {
  __shared__ double w[4];
  const int k = blockIdx.x, tid = threadIdx.x;
  if (k == 0) {
    double ss = 0.0;
    #pragma unroll
    for (int r = 0; r < 4; ++r) {
      int d = (r << 8) + tid;
      float m = (float)(musum[d] * (1.0 / 65536.0));
      mu[d] = m;
      ss += (double)m * (double)m;
    }
    int lane = tid & 63, wv = tid >> 6;
    #pragma unroll
    for (int mk = 1; mk < 64; mk <<= 1) ss += __shfl_xor(ss, mk);
    if (lane == 0) w[wv] = ss;
    __syncthreads();
    if (tid == 0) m2[0] = (float)(w[0] + w[1] + w[2] + w[3]);
  } else {
    #pragma unroll
    for (int r = 0; r < 4; ++r) mu[(k << 10) + (r << 8) + tid] = 0.f;
    if (tid == 0) m2[k] = 0.f;
  }
}

// ---------------- per-iteration kernels ----------------

__global__ __launch_bounds__(256) void kZ0(double* __restrict__ sums, int* __restrict__ counts,
                                           Scal* sc) {
  if (sc->done) return;
  int g = (blockIdx.x << 8) + threadIdx.x;
  sums[g] = 0.0;
  if (g < KMAX) counts[g] = 0;
  if (g == 0) { sc->s_all = 0.0; sc->s_far = 0.0; sc->sx2far = 0.0; sc->farcnt = 0; }
}

// assign: dist GEMM (256 pts x 64 slots per block), dmin/argmin, obj partials
__global__ __launch_bounds__(256) void kA(const float* __restrict__ X,
        const float* __restrict__ mu, const float* __restrict__ m2,
        const float* __restrict__ x2, float* __restrict__ dmin_out,
        int* __restrict__ z_out, Scal* __restrict__ sc) {
  if (sc->done) return;
  const int K = sc->K;
  constexpr int LSTR = 34;                 // row stride (floats): 8B-aligned, 2-way-max banks
  __shared__ float lX[256 * LSTR];         // 34816 B
  __shared__ float lMu[KMAX * LSTR];       // 8704 B
  __shared__ double wred[12];
  __shared__ int wfc[4];
  const int tid = threadIdx.x;
  const int pg = tid & 31, kg = tid >> 5;  // thread tile: 8 pts (stride 32) x 8 slots
  const int pbase = blockIdx.x << 8;
  const bool kact = (kg << 3) < K;

  float acc[8][8];
  #pragma unroll
  for (int i = 0; i < 8; ++i)
    #pragma unroll
    for (int j = 0; j < 8; ++j) acc[i][j] = 0.f;

  for (int dc = 0; dc < DDIM; dc += 32) {
    #pragma unroll
    for (int r = 0; r < 16; ++r) {         // stage X: 256 pts x 32 d
      int idx = (r << 8) + tid;
      int p = idx >> 4, c2 = (idx & 15) << 1;
      *(float2*)&lX[p * LSTR + c2] = *(const float2*)&X[((size_t)(pbase + p) << 10) + dc + c2];
    }
    #pragma unroll
    for (int r = 0; r < 4; ++r) {          // stage mu: 64 x 32
      int idx = (r << 8) + tid;
      int k = idx >> 4, c2 = (idx & 15) << 1;
      *(float2*)&lMu[k * LSTR + c2] = *(const float2*)&mu[(k << 10) + dc + c2];
    }
    __syncthreads();
    if (kact) {
      for (int d2 = 0; d2 < 16; ++d2) {
        float2 xa[8], ma[8];
        #pragma unroll
        for (int j = 0; j < 8; ++j) ma[j] = *(const float2*)&lMu[((kg << 3) + j) * LSTR + (d2 << 1)];
        #pragma unroll
        for (int i = 0; i < 8; ++i) xa[i] = *(const float2*)&lX[((i << 5) + pg) * LSTR + (d2 << 1)];
        #pragma unroll
        for (int i = 0; i < 8; ++i)
          #pragma unroll
          for (int j = 0; j < 8; ++j)
            acc[i][j] = fmaf(xa[i].y, ma[j].y, fmaf(xa[i].x, ma[j].x, acc[i][j]));
      }
    }
    __syncthreads();
  }

  // per-thread mins, then combine across the 8 k-groups via LDS (reuse lX)
  float x2v[8];
  #pragma unroll
  for (int i = 0; i < 8; ++i) x2v[i] = x2[pbase + (i << 5) + pg];
  float m2v[8];
  #pragma unroll
  for (int j = 0; j < 8; ++j) m2v[j] = kact ? m2[(kg << 3) + j] : 0.f;

  float* rd = lX;                // 2048 floats
  int*   rk = (int*)(lX + 2048); // 2048 ints
  #pragma unroll
  for (int i = 0; i < 8; ++i) {
    float bd = INF_F; int bk = KMAX;
    if (kact) {
      #pragma unroll
      for (int j = 0; j < 8; ++j) {
        int k = (kg << 3) + j;
        if (k < K) {
          float dist = x2v[i] - 2.0f * acc[i][j] + m2v[j];
          if (dist < bd) { bd = dist; bk = k; }   // strict <: lowest k wins ties
        }
      }
    }
    rd[(tid << 3) + i] = bd;
    rk[(tid << 3) + i] = bk;
  }
  __syncthreads();
  const int ii = tid >> 5, ppg = tid & 31;       // thread <-> local point tid
  float bd = INF_F; int bk = KMAX;
  #pragma unroll
  for (int g = 0; g < 8; ++g) {                  // ascending k-groups: ties keep lower k
    int src = (((g << 5) + ppg) << 3) + ii;
    float dv = rd[src]; int kv = rk[src];
    if (dv < bd || (dv == bd && kv < bk)) { bd = dv; bk = kv; }
  }
  const bool far = bd > LAMBDA_F;
  dmin_out[pbase + tid] = bd;
  z_out[pbase + tid] = bk;
  const float x2p = x2[pbase + tid];

  double a = (double)bd;
  double f = far ? (double)bd : 0.0;
  double xf = far ? (double)x2p : 0.0;
  const int lane = tid & 63, wv = tid >> 6;
  unsigned long long bal = __ballot(far);
  int fc = __popcll(bal);
  #pragma unroll
  for (int m = 1; m < 64; m <<= 1) {
    a += __shfl_xor(a, m); f += __shfl_xor(f, m); xf += __shfl_xor(xf, m);
  }
  if (lane == 0) { wred[wv] = a; wred[4 + wv] = f; wred[8 + wv] = xf; wfc[wv] = fc; }
  __syncthreads();
  if (tid == 0) {
    unsafeAtomicAdd(&sc->s_all,  wred[0] + wred[1] + wred[2] + wred[3]);
    unsafeAtomicAdd(&sc->s_far,  wred[4] + wred[5] + wred[6] + wred[7]);
    unsafeAtomicAdd(&sc->sx2far, wred[8] + wred[9] + wred[10] + wred[11]);
    atomicAdd(&sc->farcnt, wfc[0] + wfc[1] + wfc[2] + wfc[3]);
  }
}

__global__ void kB2(Scal* sc) {
  if (threadIdx.x == 0 && blockIdx.x == 0) {
    if (sc->done) return;
    int create = (sc->farcnt > 0 && sc->K < KMAX) ? 1 : 0;
    sc->create = create;
    sc->Kc = (sc->K < KMAX - 1) ? sc->K : (KMAX - 1);
    sc->Knew = sc->K + create;
  }
}

// final z (in-place in zn) + cluster counts
__global__ __launch_bounds__(256) void kC(const float* __restrict__ dmin, int* __restrict__ zn,
                                          const Scal* __restrict__ sc, int* __restrict__ counts) {
  if (sc->done) return;
  __shared__ int cnt[KMAX];
  const int tid = threadIdx.x;
  if (tid < KMAX) cnt[tid] = 0;
  __syncthreads();
  const int p = (blockIdx.x << 8) + tid;
  int z = zn[p];
  if (sc->create && dmin[p] > LAMBDA_F) z = sc->Kc;
  zn[p] = z;
  atomicAdd(&cnt[z], 1);
  __syncthreads();
  if (tid < KMAX && cnt[tid] > 0) atomicAdd(&counts[tid], cnt[tid]);
}

// segment sums: block = (dim-chunk 256, point-chunk 1024), LDS 64x256 fp32, fp64 atomics out
__global__ __launch_bounds__(256) void kD(const float* __restrict__ X, const int* __restrict__ zn,
                                          const Scal* __restrict__ sc, double* __restrict__ sums,
                                          const int* __restrict__ counts) {
  if (sc->done) return;
  __shared__ float acc[KMAX][256];
  const int tid = threadIdx.x;
  const int dcb = blockIdx.x & 3, nb = blockIdx.x >> 2;
  const int p0 = nb << 10;
  #pragma unroll
  for (int k = 0; k < KMAX; ++k) acc[k][tid] = 0.f;
  __syncthreads();
  const float* xp = X + ((size_t)p0 << 10) + (dcb << 8) + tid;
  const int* zp = zn + p0;
  for (int p = 0; p < 1024; ++p)
    acc[zp[p]][tid] += xp[(size_t)p << 10];
  __syncthreads();
  for (int k = 0; k < KMAX; ++k)
    if (counts[k] > 0)
      unsafeAtomicAdd(&sums[(k << 10) + (dcb << 8) + tid], (double)acc[k][tid]);
}

// centroid means + m2
__global__ __launch_bounds__(256) void kE1(float* __restrict__ mu, float* __restrict__ m2,
                                           const double* __restrict__ sums,
                                           const int* __restrict__ counts,
                                           const Scal* __restrict__ sc) {
  if (sc->done) return;
  __shared__ double w[4];
  const int k = blockIdx.x, tid = threadIdx.x;
  const int c = counts[k];
  const double inv = (c > 0) ? 1.0 / (double)c : 0.0;
  double ss = 0.0;
  #pragma unroll
  for (int r = 0; r < 4; ++r) {
    int d = (r << 8) + tid;
    float m = mu[(k << 10) + d];
    if (c > 0) m = (float)(sums[(k << 10) + d] * inv);
    mu[(k << 10) + d] = m;
    ss += (double)m * (double)m;
  }
  const int lane = tid & 63, wv = tid >> 6;
  #pragma unroll
  for (int mk = 1; mk < 64; mk <<= 1) ss += __shfl_xor(ss, mk);
  if (lane == 0) w[wv] = ss;
  __syncthreads();
  if (tid == 0) m2[k] = (float)(w[0] + w[1] + w[2] + w[3]);
}

// objective + convergence; Σ_cf new_col = Σ_far x2 - farcnt * m2[Kc]
__global__ void kE2(Scal* sc, const float* __restrict__ m2) {
  if (threadIdx.x == 0 && blockIdx.x == 0) {
    if (sc->done) return;
    double obj;
    if (sc->create)
      obj = (sc->s_all - sc->s_far) + (sc->sx2far - (double)sc->farcnt * (double)m2[sc->Kc]);
    else
      obj = sc->s_all;
    obj += 1000.0 * (double)sc->Knew;
    int conv = (sc->it > 0) && (fabs(obj - sc->prev_obj) < 1e-3 * obj);
    sc->done = conv;
    sc->prev_obj = obj;
    sc->K = sc->Knew;
    sc->it += 1;
  }
}

// ---------------- host ----------------

extern "C" void kernel_launch(void* const* d_in, const int* in_sizes, int n_in,
                              void* d_out, int out_size, void* d_ws, size_t ws_size,
                              hipStream_t stream) {
  const float* X = (const float*)d_in[0];
  float* mu = (float*)d_out;                     // 64 x 1024, final output
  char* ws = (char*)d_ws;
  float*  dmin   = (float*)(ws + 0);             // 256 KB
  int*    zn     = (int*)(ws + 262144);          // 256 KB
  float*  x2     = (float*)(ws + 524288);        // 256 KB
  double* sums   = (double*)(ws + 786432);       // 512 KB
  int*    counts = (int*)(ws + 1310720);         // 256 B
  double* musum  = (double*)(ws + 1310976);      // 8 KB
  float*  m2     = (float*)(ws + 1319168);       // 256 B
  Scal*   sc     = (Scal*)(ws + 1319424);

  kZpre<<<1, 256, 0, stream>>>(sc, musum);
  kZ1<<<NPTS / 4, 256, 0, stream>>>(X, x2);
  kZ2<<<256, 256, 0, stream>>>(X, musum);
  kZ3<<<KMAX, 256, 0, stream>>>(musum, mu, m2);

  for (int t = 0; t < 50; ++t) {
    kZ0<<<256, 256, 0, stream>>>(sums, counts, sc);
    kA<<<NPTS / 256, 256, 0, stream>>>(X, mu, m2, x2, dmin, zn, sc);
    kB2<<<1, 64, 0, stream>>>(sc);
    kC<<<NPTS / 256, 256, 0, stream>>>(dmin, zn, sc, counts);
    kD<<<256, 256, 0, stream>>>(X, zn, sc, sums, counts);
    kE1<<<KMAX, 256, 0, stream>>>(mu, m2, sums, counts, sc);
    kE2<<<1, 64, 0, stream>>>(sc, m2);
  }
}

// Round 2
// 1487.950 us; speedup vs baseline: 1.1365x; 1.1365x over previous
//
#include <hip/hip_runtime.h>
#include <math.h>

// DP-means on MI355X — single persistent kernel with device-wide barrier.
// All 50 scan steps run inside one launch; on convergence the grid breaks
// (no dead launches). Arithmetic is op-for-op identical to the validated
// multi-kernel version (same rounding points / reduction orders).

#define NPTS   65536
#define DDIM   1024
#define KMAX   64
#define GRID   256
#define LAMBDA_F 1000.0f
#define INF_F  1e30f

struct Scal {
  int K, it, done, _p;
  double prev_obj;
  double s_all[2], s_far[2], sx2far[2];
  int farcnt[2];
  int counts[2][64];
};

// sense-reversal grid barrier, device (agent) scope.
// Safe: grid == 256 blocks == #CUs, 64 KB LDS/block -> all blocks co-resident.
__device__ __forceinline__ void gbar(int* cnt, int* gen) {
  __syncthreads();
  if (threadIdx.x == 0) {
    __threadfence();  // release: flush this XCD's dirty L2 lines
    int g = __hip_atomic_load(gen, __ATOMIC_RELAXED, __HIP_MEMORY_SCOPE_AGENT);
    int a = __hip_atomic_fetch_add(cnt, 1, __ATOMIC_ACQ_REL, __HIP_MEMORY_SCOPE_AGENT);
    if (a == GRID - 1) {
      __hip_atomic_store(cnt, 0, __ATOMIC_RELAXED, __HIP_MEMORY_SCOPE_AGENT);
      __hip_atomic_store(gen, g + 1, __ATOMIC_RELEASE, __HIP_MEMORY_SCOPE_AGENT);
    } else {
      while (__hip_atomic_load(gen, __ATOMIC_ACQUIRE, __HIP_MEMORY_SCOPE_AGENT) == g)
        __builtin_amdgcn_s_sleep(2);
    }
    __threadfence();  // acquire side: invalidate L1/L2 before re-reading
  }
  __syncthreads();
}

__global__ void kInit(int* bar) { bar[threadIdx.x] = 0; }

__global__ __launch_bounds__(256, 1) void kMain(
    const float* __restrict__ X, float* __restrict__ mu,
    float* __restrict__ x2, int* __restrict__ z,
    double* __restrict__ sums, double* __restrict__ musum,
    float* __restrict__ m2f, Scal* sc, int* bar) {
  __shared__ __align__(16) char smem[65536];
  const int tid = threadIdx.x;
  const int b = blockIdx.x;
  const int lane = tid & 63, wv = tid >> 6;
  int* bcnt = bar;
  int* bgen = bar + 32;

  // ---- I0: zero persistent state (ws is poisoned 0xAA before every call) ----
  sums[(b << 8) + tid] = 0.0;
  if (b == 0) {
    if (tid < 64) { sc->counts[0][tid] = 0; sc->counts[1][tid] = 0; }
    if (tid == 0) {
      sc->K = 1; sc->it = 0; sc->done = 0; sc->prev_obj = 0.0;
      for (int s2 = 0; s2 < 2; ++s2) {
        sc->s_all[s2] = 0.0; sc->s_far[s2] = 0.0; sc->sx2far[s2] = 0.0; sc->farcnt[s2] = 0;
      }
    }
  }
  if (b == 1) {
    musum[tid] = 0.0; musum[256 + tid] = 0.0;
    musum[512 + tid] = 0.0; musum[768 + tid] = 0.0;
  }
  gbar(bcnt, bgen);

  // ---- I1: x2 per point (wave-per-point) + column sums for mu0 ----
  {
    const int pbase = b << 8;
    for (int i = 0; i < 64; ++i) {
      const int p = pbase + (i << 2) + wv;
      const float* row = X + ((size_t)p << 10);
      float s = 0.f;
      #pragma unroll
      for (int c = 0; c < 4; ++c) {
        float4 v = *(const float4*)&row[(c << 8) + (lane << 2)];
        s += v.x * v.x + v.y * v.y + v.z * v.z + v.w * v.w;
      }
      #pragma unroll
      for (int m = 1; m < 64; m <<= 1) s += __shfl_xor(s, m);
      if (lane == 0) x2[p] = s;
    }
    const int dcb = b & 3, nb = b >> 2;
    const int d = (dcb << 8) + tid;
    const float* xp = X + ((size_t)nb << 20) + d;
    float s = 0.f;
    for (int p = 0; p < 1024; ++p) s += xp[(size_t)p << 10];
    unsafeAtomicAdd(&musum[d], (double)s);
  }
  gbar(bcnt, bgen);

  // ---- I2: mu[0]=mean, mu[k>0]=0, m2 ----
  if (b < KMAX) {
    double* w = (double*)smem;
    const int k = b;
    if (k == 0) {
      double ss = 0.0;
      #pragma unroll
      for (int r = 0; r < 4; ++r) {
        int d = (r << 8) + tid;
        float m = (float)(musum[d] * (1.0 / 65536.0));
        mu[d] = m;
        ss += (double)m * (double)m;
      }
      #pragma unroll
      for (int mk = 1; mk < 64; mk <<= 1) ss += __shfl_xor(ss, mk);
      if (lane == 0) w[wv] = ss;
      __syncthreads();
      if (tid == 0) m2f[0] = (float)(w[0] + w[1] + w[2] + w[3]);
    } else {
      #pragma unroll
      for (int r = 0; r < 4; ++r) mu[(k << 10) + (r << 8) + tid] = 0.f;
      if (tid == 0) m2f[k] = 0.f;
    }
  }
  gbar(bcnt, bgen);

  // ---- main loop: break on convergence (freeze semantics) ----
  for (int t = 0; t < 50; ++t) {
    const int dn = *(volatile int*)&sc->done;
    if (dn) break;
    const int K = *(volatile int*)&sc->K;
    const int Kc = (K < KMAX - 1) ? K : (KMAX - 1);
    const int slot = t & 1;

    // ---- Phase A: assign (dist GEMM) + final z + counts + obj partials ----
    {
      constexpr int LSTR = 34;
      float*  lX   = (float*)smem;             // 34816 B
      float*  lMu  = (float*)(smem + 34816);   //  8704 B
      double* wred = (double*)(smem + 43520);  //    96 B
      int*    wfc  = (int*)(smem + 43616);     //    16 B
      int*    lcnt = (int*)(smem + 43648);     //   256 B
      const int pg = tid & 31, kg = tid >> 5;
      const int pbase = b << 8;
      const bool kact = (kg << 3) < K;
      if (tid < KMAX) lcnt[tid] = 0;

      float acc[8][8];
      #pragma unroll
      for (int i = 0; i < 8; ++i)
        #pragma unroll
        for (int j = 0; j < 8; ++j) acc[i][j] = 0.f;

      for (int dc = 0; dc < DDIM; dc += 32) {
        #pragma unroll
        for (int r = 0; r < 16; ++r) {
          int idx = (r << 8) + tid;
          int p = idx >> 4, c2 = (idx & 15) << 1;
          *(float2*)&lX[p * LSTR + c2] =
              *(const float2*)&X[((size_t)(pbase + p) << 10) + dc + c2];
        }
        #pragma unroll
        for (int r = 0; r < 4; ++r) {
          int idx = (r << 8) + tid;
          int k = idx >> 4, c2 = (idx & 15) << 1;
          *(float2*)&lMu[k * LSTR + c2] = *(const float2*)&mu[(k << 10) + dc + c2];
        }
        __syncthreads();
        if (kact) {
          for (int d2 = 0; d2 < 16; ++d2) {
            float2 xa[8], ma[8];
            #pragma unroll
            for (int j = 0; j < 8; ++j)
              ma[j] = *(const float2*)&lMu[((kg << 3) + j) * LSTR + (d2 << 1)];
            #pragma unroll
            for (int i = 0; i < 8; ++i)
              xa[i] = *(const float2*)&lX[((i << 5) + pg) * LSTR + (d2 << 1)];
            #pragma unroll
            for (int i = 0; i < 8; ++i)
              #pragma unroll
              for (int j = 0; j < 8; ++j)
                acc[i][j] = fmaf(xa[i].y, ma[j].y, fmaf(xa[i].x, ma[j].x, acc[i][j]));
          }
        }
        __syncthreads();
      }

      float x2v[8];
      #pragma unroll
      for (int i = 0; i < 8; ++i) x2v[i] = x2[pbase + (i << 5) + pg];
      float m2v[8];
      #pragma unroll
      for (int j = 0; j < 8; ++j) m2v[j] = kact ? m2f[(kg << 3) + j] : 0.f;

      float* rd = lX;
      int*   rk = (int*)(lX + 2048);
      #pragma unroll
      for (int i = 0; i < 8; ++i) {
        float bd2 = INF_F; int bk2 = KMAX;
        if (kact) {
          #pragma unroll
          for (int j = 0; j < 8; ++j) {
            int k = (kg << 3) + j;
            if (k < K) {
              float dist = x2v[i] - 2.0f * acc[i][j] + m2v[j];
              if (dist < bd2) { bd2 = dist; bk2 = k; }
            }
          }
        }
        rd[(tid << 3) + i] = bd2;
        rk[(tid << 3) + i] = bk2;
      }
      __syncthreads();
      const int ii = tid >> 5, ppg = tid & 31;
      float bd = INF_F; int bk = KMAX;
      #pragma unroll
      for (int g = 0; g < 8; ++g) {
        int src = (((g << 5) + ppg) << 3) + ii;
        float dv = rd[src]; int kv = rk[src];
        if (dv < bd || (dv == bd && kv < bk)) { bd = dv; bk = kv; }
      }
      // per-point far implies any(far): final z is locally computable
      const bool far = bd > LAMBDA_F;
      const int zf = (far && (K < KMAX)) ? Kc : bk;
      z[pbase + tid] = zf;
      atomicAdd(&lcnt[zf], 1);

      const float x2p = x2[pbase + tid];
      double a = (double)bd;
      double f = far ? (double)bd : 0.0;
      double xf = far ? (double)x2p : 0.0;
      unsigned long long bal = __ballot(far);
      int fc = __popcll(bal);
      #pragma unroll
      for (int m = 1; m < 64; m <<= 1) {
        a += __shfl_xor(a, m); f += __shfl_xor(f, m); xf += __shfl_xor(xf, m);
      }
      if (lane == 0) { wred[wv] = a; wred[4 + wv] = f; wred[8 + wv] = xf; wfc[wv] = fc; }
      __syncthreads();
      if (tid == 0) {
        unsafeAtomicAdd(&sc->s_all[slot],  wred[0] + wred[1] + wred[2] + wred[3]);
        unsafeAtomicAdd(&sc->s_far[slot],  wred[4] + wred[5] + wred[6] + wred[7]);
        unsafeAtomicAdd(&sc->sx2far[slot], wred[8] + wred[9] + wred[10] + wred[11]);
        atomicAdd(&sc->farcnt[slot], wfc[0] + wfc[1] + wfc[2] + wfc[3]);
      }
      if (tid < KMAX) {
        int c = lcnt[tid];
        if (c > 0) atomicAdd(&sc->counts[slot][tid], c);
      }
    }
    gbar(bcnt, bgen);

    // ---- Phase D: segment sums (LDS 64x256 fp32 -> fp64 atomics) ----
    {
      float (*accS)[256] = (float (*)[256])(void*)smem;  // 64 KB
      const int dcb = b & 3, nb = b >> 2;
      const int p0 = nb << 10;
      #pragma unroll
      for (int k = 0; k < KMAX; ++k) accS[k][tid] = 0.f;
      __syncthreads();
      const float* xp = X + ((size_t)p0 << 10) + (dcb << 8) + tid;
      const int* zp = z + p0;
      for (int p = 0; p < 1024; ++p)
        accS[zp[p]][tid] += xp[(size_t)p << 10];
      __syncthreads();
      for (int k = 0; k < KMAX; ++k)
        if (sc->counts[slot][k] > 0)
          unsafeAtomicAdd(&sums[(k << 10) + (dcb << 8) + tid], (double)accS[k][tid]);
    }
    gbar(bcnt, bgen);

    // ---- Phase E: centroid means + m2; block Kc also does obj/convergence ----
    if (b < KMAX) {
      double* w = (double*)smem;
      const int k = b;
      const int c = sc->counts[slot][k];
      const double inv = (c > 0) ? 1.0 / (double)c : 0.0;
      double ss = 0.0;
      #pragma unroll
      for (int r = 0; r < 4; ++r) {
        int d = (r << 8) + tid;
        float m = mu[(k << 10) + d];
        if (c > 0) m = (float)(sums[(k << 10) + d] * inv);
        mu[(k << 10) + d] = m;
        sums[(k << 10) + d] = 0.0;          // reset for next iteration
        ss += (double)m * (double)m;
      }
      #pragma unroll
      for (int mk = 1; mk < 64; mk <<= 1) ss += __shfl_xor(ss, mk);
      if (lane == 0) w[wv] = ss;
      __syncthreads();
      float m2k = 0.f;
      if (tid == 0) {
        m2k = (float)(w[0] + w[1] + w[2] + w[3]);
        m2f[k] = m2k;
      }
      if (k == Kc) {  // F epilogue: obj, convergence, state update, next-slot zeroing
        if (tid < 64) sc->counts[slot ^ 1][tid] = 0;
        if (tid == 0) {
          sc->s_all[slot ^ 1] = 0.0; sc->s_far[slot ^ 1] = 0.0;
          sc->sx2far[slot ^ 1] = 0.0; sc->farcnt[slot ^ 1] = 0;
          int farc = sc->farcnt[slot];
          int create = (farc > 0 && K < KMAX) ? 1 : 0;
          int Knew = K + create;
          double obj;
          if (create)
            obj = (sc->s_all[slot] - sc->s_far[slot]) +
                  (sc->sx2far[slot] - (double)farc * (double)m2k);
          else
            obj = sc->s_all[slot];
          obj += 1000.0 * (double)Knew;
          int conv = (sc->it > 0) && (fabs(obj - sc->prev_obj) < 1e-3 * obj);
          sc->done = conv;
          sc->prev_obj = obj;
          sc->K = Knew;
          sc->it = sc->it + 1;
        }
      }
    }
    gbar(bcnt, bgen);
  }
}

// ---------------- host ----------------

extern "C" void kernel_launch(void* const* d_in, const int* in_sizes, int n_in,
                              void* d_out, int out_size, void* d_ws, size_t ws_size,
                              hipStream_t stream) {
  const float* X = (const float*)d_in[0];
  float* mu = (float*)d_out;                   // 64 x 1024 fp32 output
  char* ws = (char*)d_ws;
  float*  x2    = (float*)(ws + 0);            // 256 KB
  int*    z     = (int*)(ws + 262144);         // 256 KB
  double* sums  = (double*)(ws + 524288);      // 512 KB
  double* musum = (double*)(ws + 1048576);     // 8 KB
  float*  m2f   = (float*)(ws + 1056768);      // 256 B
  Scal*   sc    = (Scal*)(ws + 1057024);       // ~600 B
  int*    bar   = (int*)(ws + 1058048);        // 256 B

  kInit<<<1, 64, 0, stream>>>(bar);
  kMain<<<GRID, 256, 0, stream>>>(X, mu, x2, z, sums, musum, m2f, sc, bar);
}